// Round 5
// baseline (318.399 us; speedup 1.0000x reference)
//
#include <hip/hip_runtime.h>

#define NN 50000
#define NE 600000
#define DD 128
#define RR 8
#define NBASIS 4
#define NR (NN * RR)
#define KTOT 640      // 4*128 (z bases) + 128 (self feat)
#define NPB 16        // nodes per block in fused kernel

typedef float f32x4 __attribute__((ext_vector_type(4)));
typedef short bf16x8 __attribute__((ext_vector_type(8)));

static __device__ __forceinline__ unsigned short f2b(float f) {
  union { float f; unsigned u; } c; c.f = f;
  unsigned u = c.u + 0x7fffu + ((c.u >> 16) & 1u);  // RNE
  return (unsigned short)(u >> 16);
}
static __device__ __forceinline__ unsigned pack2(float lo, float hi) {
  return (unsigned)f2b(lo) | ((unsigned)f2b(hi) << 16);
}
static __device__ __forceinline__ float b2f_lo(unsigned v) {
  union { unsigned u; float f; } c; c.u = v << 16; return c.f;
}
static __device__ __forceinline__ float b2f_hi(unsigned v) {
  union { unsigned u; float f; } c; c.u = v & 0xffff0000u; return c.f;
}

// ---------------------------------------------------------------------------
// prep: bf16-convert x, build BT1/BT2, count edges per (dst,etype).
// Disjoint block ranges; all stage-1 work in one dispatch.
#define PREP_XB 12500                    // NN*DD/2 / 256
#define PREP_BT 320                      // DD*KTOT / 256
#define PREP_CNT 2344                    // ceil(NE/256)
#define PREP_TOTAL (PREP_XB + 2 * PREP_BT + PREP_CNT)

__global__ __launch_bounds__(256) void prep_kernel(
    const float* __restrict__ x, const float* __restrict__ basis1,
    const float* __restrict__ root1, const float* __restrict__ basis2,
    const float* __restrict__ root2, const int* __restrict__ dst,
    const int* __restrict__ et, unsigned* __restrict__ xb,
    unsigned short* __restrict__ BT1, unsigned short* __restrict__ BT2,
    int* __restrict__ cnt) {
  int bid = blockIdx.x;
  int t = threadIdx.x;
  if (bid < PREP_XB) {
    int i = bid * 256 + t;  // exact: NN*DD/2 = 12500*256
    float2 v = ((const float2*)x)[i];
    xb[i] = pack2(v.x, v.y);
  } else if (bid < PREP_XB + PREP_BT) {
    int idx = (bid - PREP_XB) * 256 + t;  // exact: DD*KTOT = 320*256
    int c = idx / KTOT, k = idx - c * KTOT;
    float v = (k < 512) ? basis1[(size_t)((k >> 7) * DD + (k & 127)) * DD + c]
                        : root1[(size_t)(k - 512) * DD + c];
    BT1[idx] = f2b(v);
  } else if (bid < PREP_XB + 2 * PREP_BT) {
    int idx = (bid - PREP_XB - PREP_BT) * 256 + t;
    int c = idx / KTOT, k = idx - c * KTOT;
    float v = (k < 512) ? basis2[(size_t)((k >> 7) * DD + (k & 127)) * DD + c]
                        : root2[(size_t)(k - 512) * DD + c];
    BT2[idx] = f2b(v);
  } else {
    int e = (bid - PREP_XB - 2 * PREP_BT) * 256 + t;
    if (e < NE) atomicAdd(&cnt[dst[e] * RR + et[e]], 1);
  }
}

// ---------------------------------------------------------------------------
// offs: deg from cnt row-sum, block-scan + one atomic for global base.
// CSR segment placement is order-nondeterministic but disjoint -> result
// independent of placement.
__global__ __launch_bounds__(256) void offs_kernel(
    const int* __restrict__ cnt, int2* __restrict__ od,
    int* __restrict__ curs, int* __restrict__ gcur) {
  __shared__ int s[256];
  __shared__ int base;
  int t = threadIdx.x;
  int i = blockIdx.x * 256 + t;
  int v = 0;
  if (i < NN) {
    const int4* c4 = (const int4*)cnt;
    int4 a = c4[i * 2];
    int4 b = c4[i * 2 + 1];
    v = a.x + a.y + a.z + a.w + b.x + b.y + b.z + b.w;
  }
  s[t] = v;
  __syncthreads();
  for (int off = 1; off < 256; off <<= 1) {
    int add = (t >= off) ? s[t - off] : 0;
    __syncthreads();
    s[t] += add;
    __syncthreads();
  }
  if (t == 255) base = atomicAdd(gcur, s[255]);
  __syncthreads();
  if (i < NN) {
    int o = base + s[t] - v;
    od[i] = make_int2(o, v);
    curs[i] = o;
  }
}

// ---------------------------------------------------------------------------
__global__ __launch_bounds__(256) void sort_kernel(
    const int* __restrict__ src, const int* __restrict__ dst,
    const int* __restrict__ et, int* __restrict__ curs,
    int* __restrict__ skey) {
  int e = blockIdx.x * 256 + threadIdx.x;
  if (e >= NE) return;
  int p = atomicAdd(&curs[dst[e]], 1);
  skey[p] = src[e] | (et[e] << 28);
}

// ---------------------------------------------------------------------------
// Fused aggregate + GEMM.  Block = 16 nodes, 8 waves.
// Phase A: wave aggregates 2 nodes (4x16-lane edge groups, unroll-2 -> 8
//          gathers in flight), z packed bf16 into LDS [16][648] (pad: 2-way
//          max bank aliasing).
// Phase B: wave computes 16 rows x 16 cols via mfma_f32_16x16x32_bf16 over
//          K=640; A-frag from LDS, B-frag streamed from BT (L2-resident).
template <int OUT_BF16>
__global__ __launch_bounds__(512, 6) void rgcn_fused(
    const uint4* __restrict__ featb4,   // [NN][16] bf16 rows as uint4
    const int* __restrict__ skey, const int* __restrict__ cnt,
    const float* __restrict__ comp, const int2* __restrict__ od,
    const unsigned short* __restrict__ BT,  // [128][640] bf16
    const float* __restrict__ bias, void* __restrict__ Cout) {
  __shared__ unsigned short zl[NPB][648];
  __shared__ float compl_[RR * NBASIS];
  __shared__ float ccl[NPB][RR * NBASIS];

  int tid = threadIdx.x;
  if (tid < RR * NBASIS) compl_[tid] = comp[tid];
  __syncthreads();

  int wid = tid >> 6;
  int lane = tid & 63;
  int g = lane >> 4;
  int q = lane & 15;
  int nb = blockIdx.x * NPB;

  for (int r0 = 0; r0 < 2; ++r0) {
    int row = wid * 2 + r0;
    int node = nb + row;
    int2 o_d = od[node];
    int beg = o_d.x, dg = o_d.y;

    // per-node folded coefficients: ccl[row][t*4+b] = comp[t][b]/cnt[node,t]
    if (lane < 32) {
      int c = cnt[node * RR + (lane >> 2)];
      ccl[row][lane] = compl_[lane] * (1.0f / (float)max(c, 1));
    }

    float a0[8] = {}, a1[8] = {}, a2[8] = {}, a3[8] = {};
    for (int i = g; i < dg; i += 8) {
      int k1 = skey[beg + i];
      bool has2 = (i + 4 < dg);
      int k2 = has2 ? skey[beg + i + 4] : k1;   // masked load, addr stays valid
      int t1 = ((unsigned)k1) >> 28;
      int t2 = ((unsigned)k2) >> 28;
      uint4 v1 = featb4[(size_t)(k1 & 0x0FFFFFFF) * 16 + q];
      uint4 v2 = featb4[(size_t)(k2 & 0x0FFFFFFF) * 16 + q];
      float c10 = ccl[row][t1 * 4 + 0], c11 = ccl[row][t1 * 4 + 1];
      float c12 = ccl[row][t1 * 4 + 2], c13 = ccl[row][t1 * 4 + 3];
      float sc2 = has2 ? 1.0f : 0.0f;
      float c20 = sc2 * ccl[row][t2 * 4 + 0], c21 = sc2 * ccl[row][t2 * 4 + 1];
      float c22 = sc2 * ccl[row][t2 * 4 + 2], c23 = sc2 * ccl[row][t2 * 4 + 3];
      float e1[8], e2[8];
      e1[0] = b2f_lo(v1.x); e1[1] = b2f_hi(v1.x);
      e1[2] = b2f_lo(v1.y); e1[3] = b2f_hi(v1.y);
      e1[4] = b2f_lo(v1.z); e1[5] = b2f_hi(v1.z);
      e1[6] = b2f_lo(v1.w); e1[7] = b2f_hi(v1.w);
      e2[0] = b2f_lo(v2.x); e2[1] = b2f_hi(v2.x);
      e2[2] = b2f_lo(v2.y); e2[3] = b2f_hi(v2.y);
      e2[4] = b2f_lo(v2.z); e2[5] = b2f_hi(v2.z);
      e2[6] = b2f_lo(v2.w); e2[7] = b2f_hi(v2.w);
#pragma unroll
      for (int j = 0; j < 8; ++j) {
        a0[j] += c10 * e1[j] + c20 * e2[j];
        a1[j] += c11 * e1[j] + c21 * e2[j];
        a2[j] += c12 * e1[j] + c22 * e2[j];
        a3[j] += c13 * e1[j] + c23 * e2[j];
      }
    }

    // combine the 4 edge-group partials (lanes differing in bits 4,5)
#pragma unroll
    for (int j = 0; j < 8; ++j) {
      a0[j] += __shfl_xor(a0[j], 16); a0[j] += __shfl_xor(a0[j], 32);
      a1[j] += __shfl_xor(a1[j], 16); a1[j] += __shfl_xor(a1[j], 32);
      a2[j] += __shfl_xor(a2[j], 16); a2[j] += __shfl_xor(a2[j], 32);
      a3[j] += __shfl_xor(a3[j], 16); a3[j] += __shfl_xor(a3[j], 32);
    }

    uint4 w;
    if (g == 0) {
      w.x = pack2(a0[0], a0[1]); w.y = pack2(a0[2], a0[3]);
      w.z = pack2(a0[4], a0[5]); w.w = pack2(a0[6], a0[7]);
    } else if (g == 1) {
      w.x = pack2(a1[0], a1[1]); w.y = pack2(a1[2], a1[3]);
      w.z = pack2(a1[4], a1[5]); w.w = pack2(a1[6], a1[7]);
    } else if (g == 2) {
      w.x = pack2(a2[0], a2[1]); w.y = pack2(a2[2], a2[3]);
      w.z = pack2(a2[4], a2[5]); w.w = pack2(a2[6], a2[7]);
    } else {
      w.x = pack2(a3[0], a3[1]); w.y = pack2(a3[2], a3[3]);
      w.z = pack2(a3[4], a3[5]); w.w = pack2(a3[6], a3[7]);
    }
    *(uint4*)&zl[row][g * 128 + q * 8] = w;
    if (g == 0)  // self features, cols [512,640)
      *(uint4*)&zl[row][512 + q * 8] = featb4[(size_t)node * 16 + q];
  }
  __syncthreads();

  // ---- phase B: 16x16 output tile per wave over K=640 ----
  f32x4 acc = {};
#pragma unroll 4
  for (int ks = 0; ks < 20; ++ks) {
    int ko = ks * 32 + ((lane >> 4) << 3);
    bf16x8 af = *(const bf16x8*)&zl[lane & 15][ko];
    bf16x8 bf_ =
        *(const bf16x8*)(BT + (size_t)(wid * 16 + (lane & 15)) * KTOT + ko);
    acc = __builtin_amdgcn_mfma_f32_16x16x32_bf16(af, bf_, acc, 0, 0, 0);
  }

  int col = wid * 16 + (lane & 15);
  float bb = bias[col];
#pragma unroll
  for (int j = 0; j < 4; ++j) {
    int grow = nb + ((lane >> 4) << 2) + j;
    float o = acc[j] + bb;
    if (OUT_BF16) {
      o = fmaxf(o, 0.f);
      ((unsigned short*)Cout)[(size_t)grow * DD + col] = f2b(o);
    } else {
      ((float*)Cout)[(size_t)grow * DD + col] = o;
    }
  }
}

// ---------------------------------------------------------------------------
extern "C" void kernel_launch(void* const* d_in, const int* in_sizes, int n_in,
                              void* d_out, int out_size, void* d_ws,
                              size_t ws_size, hipStream_t stream) {
  const float* x      = (const float*)d_in[0];
  const int*   eidx   = (const int*)d_in[1];
  const int*   etype  = (const int*)d_in[2];
  const float* basis1 = (const float*)d_in[3];
  const float* comp1  = (const float*)d_in[4];
  const float* root1  = (const float*)d_in[5];
  const float* bias1  = (const float*)d_in[6];
  const float* basis2 = (const float*)d_in[7];
  const float* comp2  = (const float*)d_in[8];
  const float* root2  = (const float*)d_in[9];
  const float* bias2  = (const float*)d_in[10];
  float* out = (float*)d_out;

  const int* src = eidx;
  const int* dst = eidx + NE;

  // workspace layout (16B-aligned chunk sizes)
  unsigned short* xb  = (unsigned short*)d_ws;         // [NN][128] bf16
  unsigned short* hb  = xb + (size_t)NN * DD;          // [NN][128] bf16
  unsigned short* BT1 = hb + (size_t)NN * DD;          // [128][640] bf16
  unsigned short* BT2 = BT1 + (size_t)DD * KTOT;
  int*  skey = (int*)(BT2 + (size_t)DD * KTOT);        // [NE]
  int*  cnt  = skey + NE;                              // [NR]
  int*  gcur = cnt + NR;                               // [4] (pad)
  int2* od   = (int2*)(gcur + 4);                      // [NN] (offs,deg)
  int*  curs = (int*)(od + NN);                        // [NN]

  const int NB = (NN + 255) / 256;  // 196
  const int EB = (NE + 255) / 256;  // 2344

  hipMemsetAsync(cnt, 0, (size_t)(NR + 4) * sizeof(int), stream);
  prep_kernel<<<PREP_TOTAL, 256, 0, stream>>>(
      x, basis1, root1, basis2, root2, dst, etype, (unsigned*)xb, BT1, BT2,
      cnt);
  offs_kernel<<<NB, 256, 0, stream>>>(cnt, od, curs, gcur);
  sort_kernel<<<EB, 256, 0, stream>>>(src, dst, etype, curs, skey);

  // ---- layer 1 (x -> h, relu, bf16) ----
  rgcn_fused<1><<<NN / NPB, 512, 0, stream>>>((const uint4*)xb, skey, cnt,
                                              comp1, od, BT1, bias1, hb);
  // ---- layer 2 (h -> out, f32) ----
  rgcn_fused<0><<<NN / NPB, 512, 0, stream>>>((const uint4*)hb, skey, cnt,
                                              comp2, od, BT2, bias2, out);
}

// Round 6
// 242.706 us; speedup vs baseline: 1.3119x; 1.3119x over previous
//
#include <hip/hip_runtime.h>

#define NN 50000
#define NE 600000
#define DD 128
#define RR 8
#define NBASIS 4
#define NR (NN * RR)
#define KTOT 640      // 4*128 (z bases) + 128 (self feat)
#define MPAD 50048    // 391 * 128

typedef float f32x4 __attribute__((ext_vector_type(4)));
typedef short bf16x8 __attribute__((ext_vector_type(8)));

static __device__ __forceinline__ unsigned short f2b(float f) {
  union { float f; unsigned u; } c; c.f = f;
  unsigned u = c.u + 0x7fffu + ((c.u >> 16) & 1u);  // RNE
  return (unsigned short)(u >> 16);
}
static __device__ __forceinline__ unsigned pack2(float lo, float hi) {
  return (unsigned)f2b(lo) | ((unsigned)f2b(hi) << 16);
}
static __device__ __forceinline__ float b2f_lo(unsigned v) {
  union { unsigned u; float f; } c; c.u = v << 16; return c.f;
}
static __device__ __forceinline__ float b2f_hi(unsigned v) {
  union { unsigned u; float f; } c; c.u = v & 0xffff0000u; return c.f;
}

// ---------------------------------------------------------------------------
// prep: bf16-convert x, build BT1/BT2, count edges per (dst,etype).
#define PREP_XB 12500                    // NN*DD/2 / 256
#define PREP_BT 320                      // DD*KTOT / 256
#define PREP_CNT 2344                    // ceil(NE/256)
#define PREP_TOTAL (PREP_XB + 2 * PREP_BT + PREP_CNT)

__global__ __launch_bounds__(256) void prep_kernel(
    const float* __restrict__ x, const float* __restrict__ basis1,
    const float* __restrict__ root1, const float* __restrict__ basis2,
    const float* __restrict__ root2, const int* __restrict__ dst,
    const int* __restrict__ et, unsigned* __restrict__ xb,
    unsigned short* __restrict__ BT1, unsigned short* __restrict__ BT2,
    int* __restrict__ cnt) {
  int bid = blockIdx.x;
  int t = threadIdx.x;
  if (bid < PREP_XB) {
    int i = bid * 256 + t;  // exact: NN*DD/2 = 12500*256
    float2 v = ((const float2*)x)[i];
    xb[i] = pack2(v.x, v.y);
  } else if (bid < PREP_XB + PREP_BT) {
    int idx = (bid - PREP_XB) * 256 + t;  // exact: DD*KTOT = 320*256
    int c = idx / KTOT, k = idx - c * KTOT;
    float v = (k < 512) ? basis1[(size_t)((k >> 7) * DD + (k & 127)) * DD + c]
                        : root1[(size_t)(k - 512) * DD + c];
    BT1[idx] = f2b(v);
  } else if (bid < PREP_XB + 2 * PREP_BT) {
    int idx = (bid - PREP_XB - PREP_BT) * 256 + t;
    int c = idx / KTOT, k = idx - c * KTOT;
    float v = (k < 512) ? basis2[(size_t)((k >> 7) * DD + (k & 127)) * DD + c]
                        : root2[(size_t)(k - 512) * DD + c];
    BT2[idx] = f2b(v);
  } else {
    int e = (bid - PREP_XB - 2 * PREP_BT) * 256 + t;
    if (e < NE) atomicAdd(&cnt[dst[e] * RR + et[e]], 1);
  }
}

// ---------------------------------------------------------------------------
// offs: deg from cnt row-sum, block-scan + one atomic for global base.
// Segment placement is order-nondeterministic but disjoint -> result
// independent of placement.
__global__ __launch_bounds__(256) void offs_kernel(
    const int* __restrict__ cnt, int2* __restrict__ od,
    int* __restrict__ curs, int* __restrict__ gcur) {
  __shared__ int s[256];
  __shared__ int base;
  int t = threadIdx.x;
  int i = blockIdx.x * 256 + t;
  int v = 0;
  if (i < NN) {
    const int4* c4 = (const int4*)cnt;
    int4 a = c4[i * 2];
    int4 b = c4[i * 2 + 1];
    v = a.x + a.y + a.z + a.w + b.x + b.y + b.z + b.w;
  }
  s[t] = v;
  __syncthreads();
  for (int off = 1; off < 256; off <<= 1) {
    int add = (t >= off) ? s[t - off] : 0;
    __syncthreads();
    s[t] += add;
    __syncthreads();
  }
  if (t == 255) base = atomicAdd(gcur, s[255]);
  __syncthreads();
  if (i < NN) {
    int o = base + s[t] - v;
    od[i] = make_int2(o, v);
    curs[i] = o;
  }
}

// ---------------------------------------------------------------------------
__global__ __launch_bounds__(256) void sort_kernel(
    const int* __restrict__ src, const int* __restrict__ dst,
    const int* __restrict__ et, int* __restrict__ curs,
    int* __restrict__ skey) {
  int e = blockIdx.x * 256 + threadIdx.x;
  if (e >= NE) return;
  int p = atomicAdd(&curs[dst[e]], 1);
  skey[p] = src[e] | (et[e] << 28);
}

// ---------------------------------------------------------------------------
// One wave per dst node, 4x16-lane edge groups, 4-deep unroll:
// 16 independent 256B feature gathers in flight per wave.
// Lane q owns feature bytes [q*16, q*16+16).  Coeffs comp[t][b]/cnt[node,t]
// staged per-node in LDS (broadcast ds_read_b128 per edge).
__global__ __launch_bounds__(256) void agg_kernel(
    const uint4* __restrict__ featb4,   // [NN][16] bf16 rows as uint4
    const int* __restrict__ skey, const int* __restrict__ cnt,
    const float* __restrict__ comp, const int2* __restrict__ od,
    uint4* __restrict__ Ab4) {          // [MPAD][80]
  __shared__ float ccl[4][RR * NBASIS];
  int tid = threadIdx.x;
  int w = tid >> 6;
  int lane = tid & 63;
  int node = blockIdx.x * 4 + w;        // 12500 * 4 == NN exactly
  int g = lane >> 4;
  int q = lane & 15;

  int2 o_d = od[node];
  int beg = o_d.x, dg = o_d.y;

  if (lane < RR * NBASIS) {
    int c = cnt[node * RR + (lane >> 2)];
    ccl[w][lane] = comp[lane] * (1.0f / (float)max(c, 1));
  }
  __syncthreads();

  float a0[8] = {}, a1[8] = {}, a2[8] = {}, a3[8] = {};

  int last = beg + dg - 1;  // only used when dg > 0
  const float4* cc4 = (const float4*)ccl[w];
  for (int i = g; i < dg; i += 16) {
    int p0 = beg + i;
    int p1 = min(p0 + 4, last);
    int p2 = min(p0 + 8, last);
    int p3 = min(p0 + 12, last);
    int k0 = skey[p0], k1 = skey[p1], k2 = skey[p2], k3 = skey[p3];
    uint4 v0 = featb4[(size_t)(k0 & 0x0FFFFFFF) * 16 + q];
    uint4 v1 = featb4[(size_t)(k1 & 0x0FFFFFFF) * 16 + q];
    uint4 v2 = featb4[(size_t)(k2 & 0x0FFFFFFF) * 16 + q];
    uint4 v3 = featb4[(size_t)(k3 & 0x0FFFFFFF) * 16 + q];
    float s1 = (i + 4 < dg) ? 1.f : 0.f;
    float s2 = (i + 8 < dg) ? 1.f : 0.f;
    float s3 = (i + 12 < dg) ? 1.f : 0.f;
    float4 c0 = cc4[((unsigned)k0) >> 28];
    float4 c1 = cc4[((unsigned)k1) >> 28];
    float4 c2 = cc4[((unsigned)k2) >> 28];
    float4 c3 = cc4[((unsigned)k3) >> 28];
    c1.x *= s1; c1.y *= s1; c1.z *= s1; c1.w *= s1;
    c2.x *= s2; c2.y *= s2; c2.z *= s2; c2.w *= s2;
    c3.x *= s3; c3.y *= s3; c3.z *= s3; c3.w *= s3;

    float e[8], f[8];
    e[0] = b2f_lo(v0.x); e[1] = b2f_hi(v0.x);
    e[2] = b2f_lo(v0.y); e[3] = b2f_hi(v0.y);
    e[4] = b2f_lo(v0.z); e[5] = b2f_hi(v0.z);
    e[6] = b2f_lo(v0.w); e[7] = b2f_hi(v0.w);
    f[0] = b2f_lo(v1.x); f[1] = b2f_hi(v1.x);
    f[2] = b2f_lo(v1.y); f[3] = b2f_hi(v1.y);
    f[4] = b2f_lo(v1.z); f[5] = b2f_hi(v1.z);
    f[6] = b2f_lo(v1.w); f[7] = b2f_hi(v1.w);
#pragma unroll
    for (int j = 0; j < 8; ++j) {
      a0[j] += c0.x * e[j] + c1.x * f[j];
      a1[j] += c0.y * e[j] + c1.y * f[j];
      a2[j] += c0.z * e[j] + c1.z * f[j];
      a3[j] += c0.w * e[j] + c1.w * f[j];
    }
    e[0] = b2f_lo(v2.x); e[1] = b2f_hi(v2.x);
    e[2] = b2f_lo(v2.y); e[3] = b2f_hi(v2.y);
    e[4] = b2f_lo(v2.z); e[5] = b2f_hi(v2.z);
    e[6] = b2f_lo(v2.w); e[7] = b2f_hi(v2.w);
    f[0] = b2f_lo(v3.x); f[1] = b2f_hi(v3.x);
    f[2] = b2f_lo(v3.y); f[3] = b2f_hi(v3.y);
    f[4] = b2f_lo(v3.z); f[5] = b2f_hi(v3.z);
    f[6] = b2f_lo(v3.w); f[7] = b2f_hi(v3.w);
#pragma unroll
    for (int j = 0; j < 8; ++j) {
      a0[j] += c2.x * e[j] + c3.x * f[j];
      a1[j] += c2.y * e[j] + c3.y * f[j];
      a2[j] += c2.z * e[j] + c3.z * f[j];
      a3[j] += c2.w * e[j] + c3.w * f[j];
    }
  }

  // combine the 4 edge-group partials (lanes differing in bits 4,5)
#pragma unroll
  for (int j = 0; j < 8; ++j) {
    a0[j] += __shfl_xor(a0[j], 16); a0[j] += __shfl_xor(a0[j], 32);
    a1[j] += __shfl_xor(a1[j], 16); a1[j] += __shfl_xor(a1[j], 32);
    a2[j] += __shfl_xor(a2[j], 16); a2[j] += __shfl_xor(a2[j], 32);
    a3[j] += __shfl_xor(a3[j], 16); a3[j] += __shfl_xor(a3[j], 32);
  }

  uint4* row = Ab4 + (size_t)node * 80;
  uint4 wv;
  if (g == 0) {
    wv.x = pack2(a0[0], a0[1]); wv.y = pack2(a0[2], a0[3]);
    wv.z = pack2(a0[4], a0[5]); wv.w = pack2(a0[6], a0[7]);
  } else if (g == 1) {
    wv.x = pack2(a1[0], a1[1]); wv.y = pack2(a1[2], a1[3]);
    wv.z = pack2(a1[4], a1[5]); wv.w = pack2(a1[6], a1[7]);
  } else if (g == 2) {
    wv.x = pack2(a2[0], a2[1]); wv.y = pack2(a2[2], a2[3]);
    wv.z = pack2(a2[4], a2[5]); wv.w = pack2(a2[6], a2[7]);
  } else {
    wv.x = pack2(a3[0], a3[1]); wv.y = pack2(a3[2], a3[3]);
    wv.z = pack2(a3[4], a3[5]); wv.w = pack2(a3[6], a3[7]);
  }
  row[g * 16 + q] = wv;                      // basis g, cols [g*128 + q*8 ...)
  if (g == 0) row[64 + q] = featb4[(size_t)node * 16 + q];  // self feat
}

// ---------------------------------------------------------------------------
// C[M,128] = A[M,640]bf16 @ BT^T (BT is [128 cols][640 k] bf16), +bias.
// 128x128 tile, BK=64, 4 waves 2x2, mfma_f32_16x16x32_bf16, 4x4 frags/wave.
template <int OUT_BF16>
__global__ __launch_bounds__(256) void gemm_mfma(
    const unsigned short* __restrict__ Ab, const unsigned short* __restrict__ BT,
    const float* __restrict__ bias, void* __restrict__ Cout) {
  __shared__ unsigned short As[128][64];  // [row][k]
  __shared__ unsigned short Bs[128][64];  // [col][k]

  int tid = threadIdx.x;
  int row0 = blockIdx.x * 128;
  int lane = tid & 63;
  int wid = tid >> 6;
  int wr = (wid >> 1) * 64;
  int wc = (wid & 1) * 64;

  f32x4 acc[4][4] = {};

  for (int kt = 0; kt < KTOT; kt += 64) {
#pragma unroll
    for (int i = 0; i < 4; ++i) {
      int off = i * 256 + tid;      // 16B chunk index, 0..1023
      int r = off >> 3;             // row (As) / col (Bs)
      int ke = (off & 7) << 3;      // bf16 element offset in [0,64)
      *(uint4*)((unsigned short*)As + (size_t)off * 8) =
          *(const uint4*)(Ab + (size_t)(row0 + r) * KTOT + kt + ke);
      *(uint4*)((unsigned short*)Bs + (size_t)off * 8) =
          *(const uint4*)(BT + (size_t)r * KTOT + kt + ke);
    }
    __syncthreads();

#pragma unroll
    for (int kk = 0; kk < 2; ++kk) {
      int ko = kk * 32 + ((lane >> 4) << 3);
      bf16x8 a[4], b[4];
#pragma unroll
      for (int m = 0; m < 4; ++m)
        a[m] = *(const bf16x8*)&As[wr + m * 16 + (lane & 15)][ko];
#pragma unroll
      for (int n = 0; n < 4; ++n)
        b[n] = *(const bf16x8*)&Bs[wc + n * 16 + (lane & 15)][ko];
#pragma unroll
      for (int m = 0; m < 4; ++m)
#pragma unroll
        for (int n = 0; n < 4; ++n)
          acc[m][n] = __builtin_amdgcn_mfma_f32_16x16x32_bf16(
              a[m], b[n], acc[m][n], 0, 0, 0);
    }
    __syncthreads();
  }

#pragma unroll
  for (int n = 0; n < 4; ++n) {
    int col = wc + n * 16 + (lane & 15);
    float bb = bias[col];
#pragma unroll
    for (int m = 0; m < 4; ++m) {
      f32x4 v = acc[m][n];
#pragma unroll
      for (int j = 0; j < 4; ++j) {
        int row = row0 + wr + m * 16 + ((lane >> 4) << 2) + j;
        if (row < NN) {
          float o = v[j] + bb;
          if (OUT_BF16) {
            o = fmaxf(o, 0.f);
            ((unsigned short*)Cout)[(size_t)row * DD + col] = f2b(o);
          } else {
            ((float*)Cout)[(size_t)row * DD + col] = o;
          }
        }
      }
    }
  }
}

// ---------------------------------------------------------------------------
extern "C" void kernel_launch(void* const* d_in, const int* in_sizes, int n_in,
                              void* d_out, int out_size, void* d_ws,
                              size_t ws_size, hipStream_t stream) {
  const float* x      = (const float*)d_in[0];
  const int*   eidx   = (const int*)d_in[1];
  const int*   etype  = (const int*)d_in[2];
  const float* basis1 = (const float*)d_in[3];
  const float* comp1  = (const float*)d_in[4];
  const float* root1  = (const float*)d_in[5];
  const float* bias1  = (const float*)d_in[6];
  const float* basis2 = (const float*)d_in[7];
  const float* comp2  = (const float*)d_in[8];
  const float* root2  = (const float*)d_in[9];
  const float* bias2  = (const float*)d_in[10];
  float* out = (float*)d_out;

  const int* src = eidx;
  const int* dst = eidx + NE;

  // workspace layout (16B-aligned chunk sizes)
  unsigned short* Ab  = (unsigned short*)d_ws;         // [MPAD][640] bf16
  unsigned short* xb  = Ab + (size_t)MPAD * KTOT;      // [NN][128] bf16
  unsigned short* hb  = xb + (size_t)NN * DD;          // [NN][128] bf16
  unsigned short* BT1 = hb + (size_t)NN * DD;          // [128][640] bf16
  unsigned short* BT2 = BT1 + (size_t)DD * KTOT;
  int*  skey = (int*)(BT2 + (size_t)DD * KTOT);        // [NE]
  int*  cnt  = skey + NE;                              // [NR]
  int*  gcur = cnt + NR;                               // [4] (pad)
  int2* od   = (int2*)(gcur + 4);                      // [NN] (offs,deg)
  int*  curs = (int*)(od + NN);                        // [NN]

  const int NB = (NN + 255) / 256;  // 196
  const int EB = (NE + 255) / 256;  // 2344

  hipMemsetAsync(cnt, 0, (size_t)(NR + 4) * sizeof(int), stream);
  prep_kernel<<<PREP_TOTAL, 256, 0, stream>>>(
      x, basis1, root1, basis2, root2, dst, etype, (unsigned*)xb, BT1, BT2,
      cnt);
  offs_kernel<<<NB, 256, 0, stream>>>(cnt, od, curs, gcur);
  sort_kernel<<<EB, 256, 0, stream>>>(src, dst, etype, curs, skey);

  int agg_blocks = NN / 4;        // 12500
  int gemm_blocks = MPAD / 128;   // 391

  // ---- layer 1 (x -> h, relu, bf16) ----
  agg_kernel<<<agg_blocks, 256, 0, stream>>>((const uint4*)xb, skey, cnt,
                                             comp1, od, (uint4*)Ab);
  gemm_mfma<1><<<gemm_blocks, 256, 0, stream>>>(Ab, BT1, bias1, hb);
  // ---- layer 2 (h -> out, f32) ----
  agg_kernel<<<agg_blocks, 256, 0, stream>>>((const uint4*)hb, skey, cnt,
                                             comp2, od, (uint4*)Ab);
  gemm_mfma<0><<<gemm_blocks, 256, 0, stream>>>(Ab, BT2, bias2, out);
}